// Round 10
// baseline (1066.439 us; speedup 1.0000x reference)
//
#include <hip/hip_runtime.h>
#include <math.h>
#include <stdint.h>

#define TSTEPS 200
#define BATCH  256
#define XDIM   24
#define ADIM   8
#define INDIM  32
#define HID    512
#define OUTD   64

#define NBT 8      // batch teams
#define NUT 32     // unit-tile blocks per team
#define BT  32     // batch rows per block
#define UT  16     // hidden units per block
#define KK_N 17    // K chunks of 32 (kk0 = xa from regs, kk1..16 = h from LDS)

// ---- workspace byte layout ----
#define XA_OFF   0
#define XA_BYTES (TSTEPS*BATCH*INDIM*2)              // bf16 [x*mask|a]
#define HB_BYTES (BATCH*HID*2)                       // bf16 h
#define HB_OFF(i) (XA_OFF + XA_BYTES + (size_t)(i)*HB_BYTES)   // ring of 3
#define HF_OFF   (XA_OFF + XA_BYTES + 3*(size_t)HB_BYTES)      // final h fp32

// ---- LDS byte layout ----
#define ROWB 1040                     // 1024 B h + 16 B pad
#define IN_BYTES  (BT*ROWB)           // 33,280 ; double-buffered
#define SCR_OFF   (2*IN_BYTES)        // 66,560 ; per-wave 1 KB scratch
#define LDS_TOTAL 83968               // pad >80KB -> 1 block/CU

#define SENT 0xFFFFFFFFu

typedef __attribute__((ext_vector_type(8))) short bf16x8;
typedef __attribute__((ext_vector_type(4))) float f32x4;

__device__ __forceinline__ unsigned short f2bf(float f) {
    union { float f; unsigned u; } c; c.f = f;
    unsigned u = c.u;
    return (unsigned short)((u + 0x7fffu + ((u >> 16) & 1u)) >> 16);
}
__device__ __forceinline__ bf16x8 pack8(const float* p) {
    float4 lo = *(const float4*)p, hi = *(const float4*)(p + 4);
    union { unsigned short s[8]; bf16x8 v; } u;
    u.s[0] = f2bf(lo.x); u.s[1] = f2bf(lo.y); u.s[2] = f2bf(lo.z); u.s[3] = f2bf(lo.w);
    u.s[4] = f2bf(hi.x); u.s[5] = f2bf(hi.y); u.s[6] = f2bf(hi.z); u.s[7] = f2bf(hi.w);
    return u.v;
}
__device__ __forceinline__ unsigned long long llc_load64(const unsigned long long* p) {
    return __hip_atomic_load(p, __ATOMIC_RELAXED, __HIP_MEMORY_SCOPE_AGENT);
}
__device__ __forceinline__ void llc_store64(unsigned long long* p, unsigned long long v) {
    __hip_atomic_store(p, v, __ATOMIC_RELAXED, __HIP_MEMORY_SCOPE_AGENT);
}

// ---------------------------------------------------------------------------
// precompute: xa bf16; hbuf0 = 0 (h at s=0), hbuf1/2 = sentinel
__global__ __launch_bounds__(256) void precompute_kernel(
    const float* __restrict__ x, const float* __restrict__ a,
    const float* __restrict__ mask, uint8_t* __restrict__ ws)
{
    unsigned short* xa = (unsigned short*)(ws + XA_OFF);
    const int n = TSTEPS * BATCH * INDIM;
    for (int e = blockIdx.x * 256 + threadIdx.x; e < n; e += gridDim.x * 256) {
        int t = e / (BATCH * INDIM);
        int r = e - t * (BATCH * INDIM);
        int b = r >> 5, j = r & 31;
        float v;
        if (j < XDIM) v = x[(t * BATCH + b) * XDIM + j] * mask[(t * BATCH + b) * XDIM + j];
        else          v = a[(t * BATCH + b) * ADIM + (j - XDIM)];
        xa[e] = f2bf(v);
    }
    unsigned* h0 = (unsigned*)(ws + HB_OFF(0));
    unsigned* h1 = (unsigned*)(ws + HB_OFF(1));
    unsigned* h2 = (unsigned*)(ws + HB_OFF(2));
    const int hn = HB_BYTES / 4;
    for (int e = blockIdx.x * 256 + threadIdx.x; e < hn; e += gridDim.x * 256) {
        h0[e] = 0u; h1[e] = SENT; h2[e] = SENT;
    }
}

// ---------------------------------------------------------------------------
// persistent LSTM: 256 blocks = 8 teams x 32 unit-blocks, 512 thr (8 waves).
// Team = XCD-aligned (bt = bid & 7 under round-robin dispatch; perf-only).
// Weights in VGPRs; xa A-fragment per-lane from global (kk0 MFMA pre-poll);
// h staged via LDS with INCREMENTAL verified-chunk writes; sentinel-reset
// moved after the barrier (drains under MFMA phase, re-ordered before the
// h store by an explicit vmcnt(0)); dual-accumulator K loop (8-deep chains).
__global__ __launch_bounds__(512, 1) void lstm_persist_kernel(
    const float* __restrict__ W_ih, const float* __restrict__ W_hh,
    const float* __restrict__ b_ih, const float* __restrict__ b_hh,
    uint8_t* __restrict__ ws)
{
    __shared__ __align__(16) uint8_t smem[LDS_TOTAL];
    const int tid = threadIdx.x;
    const int bid = blockIdx.x;
    const int bt = bid & 7;            // team = XCD id (round-robin heuristic)
    const int ut = bid >> 3;           // unit tile 0..31
    const int b0 = bt * BT;
    const int ug0 = ut * UT;

    const unsigned short* xab = (const unsigned short*)(ws + XA_OFF);
    unsigned long long* hb[3] = {
        (unsigned long long*)(ws + HB_OFF(0)),
        (unsigned long long*)(ws + HB_OFF(1)),
        (unsigned long long*)(ws + HB_OFF(2)) };
    float* hfinal = (float*)(ws + HF_OFF);

    const int w  = tid >> 6, l = tid & 63;
    const int mt = w >> 2;             // m-tile (16 batch rows)
    const int ct = w & 3;              // col-tile: units ct*4..+3, all 4 gates
    const int c  = l & 15;             // MFMA col: gate c>>2, unit-sub c&3
    const int kq = l >> 4;             // k-quad
    const int grow = (c >> 2) * HID + ug0 + ct * 4 + (c & 3);

    // ---- B fragments -> registers (constant all 200 steps) ----
    bf16x8 wb[KK_N];
    wb[0] = pack8(W_ih + (size_t)grow * INDIM + kq * 8);
#pragma unroll
    for (int kk = 1; kk < KK_N; ++kk)
        wb[kk] = pack8(W_hh + (size_t)grow * HID + (kk - 1) * 32 + kq * 8);
    const float bias = b_ih[grow] + b_hh[grow];

    const int du = l & 3, rs = l >> 2;           // pointwise (unit-sub, row)
    const int prow = tid >> 4, pcol = tid & 15;  // staging (row, slot)
    float c_reg = 0.0f;

    float* scr = (float*)(smem + SCR_OFF + w * 1024);

    // per-lane xa A-fragment for s=0 (t = TSTEPS-1): row mt*16+c, k = kq*8..+8
    const int arow = mt * 16 + c;
    bf16x8 af_cur = *(const bf16x8*)(xab +
        ((size_t)(TSTEPS - 1) * BATCH + b0 + arow) * 32 + kq * 8);

    for (int s = 0; s < TSTEPS; ++s) {
        uint8_t* inb = smem + (s & 1) * IN_BYTES;

        // ---- kk0 (xa) MFMA from registers, before the poll ----
        f32x4 acc = { bias, bias, bias, bias };
        acc = __builtin_amdgcn_mfma_f32_16x16x32_bf16(af_cur, wb[0], acc, 0, 0, 0);
        // prefetch next step's xa fragment (L2-resident)
        if (s < TSTEPS - 1)
            af_cur = *(const bf16x8*)(xab +
                ((size_t)(TSTEPS - 2 - s) * BATCH + b0 + arow) * 32 + kq * 8);

        // ---- poll h(s), staging each chunk to LDS as soon as verified ----
        {
            const unsigned long long* hr = hb[s % 3] + (((size_t)(b0 + prow)) << 7);
            unsigned long long vals[8];
            unsigned vm = 0;
#pragma unroll
            for (int j = 0; j < 8; ++j) vals[j] = llc_load64(hr + pcol + 16 * j);
            int rounds = 0;
            while (true) {
#pragma unroll
                for (int j = 0; j < 8; ++j) {
                    if (!(vm & (1u << j))) {
                        unsigned lo = (unsigned)vals[j];
                        unsigned hi = (unsigned)(vals[j] >> 32);
                        if (lo != SENT && hi != SENT) {
                            vm |= 1u << j;
                            *(unsigned long long*)(inb + prow * ROWB +
                                (pcol + 16 * j) * 8) = vals[j];
                        }
                    }
                }
                if (vm == 0xFFu || rounds > (1 << 20)) break;
                __builtin_amdgcn_s_sleep(1);
                ++rounds;
#pragma unroll
                for (int j = 0; j < 8; ++j)
                    if (!(vm & (1u << j))) vals[j] = llc_load64(hr + pcol + 16 * j);
            }
        }

        __syncthreads();

        // ---- sentinel-reset ring (s+2)%3 AFTER barrier: overlapped with MFMA.
        // Safe: our poll of h(s) succeeding implies every team block passed its
        // step-s barrier-preceding poll of (s+2)%3 (their h(s) stores come after
        // their barriers). Drain is enforced before our h(s+1) store below.
        if (s >= 1 && tid < 128) {
            unsigned long long* rb = hb[(s + 2) % 3]
                + (((size_t)(b0 + (tid >> 2))) << 7) + ut * 4 + (tid & 3);
            llc_store64(rb, ~0ULL);
        }

        // ---- MFMA kk1..16: dual accumulators (two 8-deep chains) ----
        const uint8_t* ab = inb + arow * ROWB + kq * 16;
        f32x4 acc1 = { 0.f, 0.f, 0.f, 0.f };
#pragma unroll
        for (int kk = 1; kk < KK_N; kk += 2) {
            bf16x8 afA = *(const bf16x8*)(ab + (kk - 1) * 64);
            acc  = __builtin_amdgcn_mfma_f32_16x16x32_bf16(afA, wb[kk], acc, 0, 0, 0);
            bf16x8 afB = *(const bf16x8*)(ab + kk * 64);
            acc1 = __builtin_amdgcn_mfma_f32_16x16x32_bf16(afB, wb[kk + 1], acc1, 0, 0, 0);
        }
        acc = acc + acc1;

        // ---- in-wave gate transpose via per-wave scratch (no barrier) ----
        *(f32x4*)(scr + l * 4) = acc;
        float gi = scr[(((rs >> 2) * 16 +  0 + du) << 2) + (rs & 3)];
        float gf = scr[(((rs >> 2) * 16 +  4 + du) << 2) + (rs & 3)];
        float gg = scr[(((rs >> 2) * 16 +  8 + du) << 2) + (rs & 3)];
        float go = scr[(((rs >> 2) * 16 + 12 + du) << 2) + (rs & 3)];

        float i_ = 1.0f / (1.0f + __expf(-gi));
        float f_ = 1.0f / (1.0f + __expf(-gf));
        float o_ = 1.0f / (1.0f + __expf(-go));
        float g_ = 1.0f - 2.0f / (__expf(2.0f * gg) + 1.0f);
        c_reg = f_ * c_reg + i_ * g_;
        float h_ = o_ * (1.0f - 2.0f / (__expf(2.0f * c_reg) + 1.0f));

        const int grow_b = b0 + mt * 16 + rs;          // global batch row
        if (s < TSTEPS - 1) {
            // pack this wave's 4 units -> u64, store by du==0 lanes
            unsigned v = (unsigned)f2bf(h_);
            unsigned t1 = (unsigned)__shfl_xor((int)v, 1);
            unsigned packed = v | (t1 << 16);
            unsigned hi = (unsigned)__shfl_xor((int)packed, 2);
            // ensure our sentinel-resets are globally visible before h(s+1):
            // h(s+2) producers are gated on observing h(s+1), so this order
            // guarantees no reset lands on fresh h(s+2) data.
            asm volatile("s_waitcnt vmcnt(0)" ::: "memory");
            if (du == 0)
                llc_store64(hb[(s + 1) % 3] + (size_t)grow_b * 128 + ut * 4 + ct,
                            (unsigned long long)packed | ((unsigned long long)hi << 32));
        } else {
            hfinal[(size_t)grow_b * HID + ug0 + ct * 4 + du] = h_;
        }
    }
}

// ---------------------------------------------------------------------------
// heads: mu = exp(h@lin_w.T + lin_b)/10 ; log_var = h@lv_w.T + lv_b - 5
__global__ __launch_bounds__(128) void head_kernel(
    const float* __restrict__ h,
    const float* __restrict__ lin_w, const float* __restrict__ lin_b,
    const float* __restrict__ lv_w,  const float* __restrict__ lv_b,
    float* __restrict__ out)
{
    __shared__ float hl[HID];
    const int b = blockIdx.x, tid = threadIdx.x;
    for (int k = tid; k < HID; k += 128) hl[k] = h[b * HID + k];
    __syncthreads();

    const float* W = (tid < 64) ? lin_w : lv_w;
    const int j = tid & 63;
    const float4* W4 = (const float4*)(W + j * HID);
    float acc = 0.0f;
    for (int k4 = 0; k4 < HID / 4; ++k4) {
        float4 wv = W4[k4];
        float4 hv = *(const float4*)(hl + k4 * 4);
        acc += wv.x * hv.x + wv.y * hv.y + wv.z * hv.z + wv.w * hv.w;
    }

    if (tid < 64) {
        out[b * OUTD + j] = __expf(acc + lin_b[j]) * 0.1f;
    } else {
        out[BATCH * OUTD + b * OUTD + j] = acc + lv_b[j] - 5.0f;
    }
}

// ---------------------------------------------------------------------------
extern "C" void kernel_launch(void* const* d_in, const int* in_sizes, int n_in,
                              void* d_out, int out_size, void* d_ws, size_t ws_size,
                              hipStream_t stream)
{
    const float* x     = (const float*)d_in[0];
    const float* a     = (const float*)d_in[1];
    const float* mask  = (const float*)d_in[2];
    const float* W_ih  = (const float*)d_in[3];
    const float* W_hh  = (const float*)d_in[4];
    const float* b_ih  = (const float*)d_in[5];
    const float* b_hh  = (const float*)d_in[6];
    const float* lin_w = (const float*)d_in[7];
    const float* lin_b = (const float*)d_in[8];
    const float* lv_w  = (const float*)d_in[9];
    const float* lv_b  = (const float*)d_in[10];

    uint8_t* ws = (uint8_t*)d_ws;

    precompute_kernel<<<512, 256, 0, stream>>>(x, a, mask, ws);
    lstm_persist_kernel<<<NBT * NUT, 512, 0, stream>>>(W_ih, W_hh, b_ih, b_hh, ws);
    head_kernel<<<BATCH, 128, 0, stream>>>((const float*)(ws + HF_OFF),
                                           lin_w, lin_b, lv_w, lv_b, (float*)d_out);
}

// Round 11
// 657.450 us; speedup vs baseline: 1.6221x; 1.6221x over previous
//
#include <hip/hip_runtime.h>
#include <math.h>
#include <stdint.h>

#define TSTEPS 200
#define BATCH  256
#define XDIM   24
#define ADIM   8
#define INDIM  32
#define HID    512
#define OUTD   64

#define NBT 8      // batch teams
#define NUT 32     // unit-tile blocks per team
#define BT  32     // batch rows per block
#define UT  16     // hidden units per block
#define KK_N 17    // K chunks of 32 (kk0 = xa from regs, kk1..16 = h from LDS)

// ---- workspace byte layout ----
#define XA_OFF   0
#define XA_BYTES (TSTEPS*BATCH*INDIM*2)              // bf16 [x*mask|a]
#define HB_BYTES (BATCH*HID*2)                       // bf16 h
#define HB_OFF(i) (XA_OFF + XA_BYTES + (size_t)(i)*HB_BYTES)   // ring of 3
#define HF_OFF   (XA_OFF + XA_BYTES + 3*(size_t)HB_BYTES)      // final h fp32

// ---- LDS byte layout ----
#define ROWB 1040                     // 1024 B h + 16 B pad
#define IN_BYTES  (BT*ROWB)           // 33,280 ; double-buffered
#define SCR_OFF   (2*IN_BYTES)        // 66,560 ; per-wave 1 KB scratch
#define LDS_TOTAL 83968               // pad >80KB -> 1 block/CU

#define SENT 0xFFFFFFFFu

typedef __attribute__((ext_vector_type(8))) short bf16x8;
typedef __attribute__((ext_vector_type(4))) float f32x4;

__device__ __forceinline__ unsigned short f2bf(float f) {
    union { float f; unsigned u; } c; c.f = f;
    unsigned u = c.u;
    return (unsigned short)((u + 0x7fffu + ((u >> 16) & 1u)) >> 16);
}
__device__ __forceinline__ bf16x8 pack8(const float* p) {
    float4 lo = *(const float4*)p, hi = *(const float4*)(p + 4);
    union { unsigned short s[8]; bf16x8 v; } u;
    u.s[0] = f2bf(lo.x); u.s[1] = f2bf(lo.y); u.s[2] = f2bf(lo.z); u.s[3] = f2bf(lo.w);
    u.s[4] = f2bf(hi.x); u.s[5] = f2bf(hi.y); u.s[6] = f2bf(hi.z); u.s[7] = f2bf(hi.w);
    return u.v;
}
__device__ __forceinline__ unsigned long long llc_load64(const unsigned long long* p) {
    return __hip_atomic_load(p, __ATOMIC_RELAXED, __HIP_MEMORY_SCOPE_AGENT);
}
__device__ __forceinline__ void llc_store64(unsigned long long* p, unsigned long long v) {
    __hip_atomic_store(p, v, __ATOMIC_RELAXED, __HIP_MEMORY_SCOPE_AGENT);
}

// ---------------------------------------------------------------------------
// precompute: xa bf16; hbuf0 = 0 (h at s=0), hbuf1/2 = sentinel
__global__ __launch_bounds__(256) void precompute_kernel(
    const float* __restrict__ x, const float* __restrict__ a,
    const float* __restrict__ mask, uint8_t* __restrict__ ws)
{
    unsigned short* xa = (unsigned short*)(ws + XA_OFF);
    const int n = TSTEPS * BATCH * INDIM;
    for (int e = blockIdx.x * 256 + threadIdx.x; e < n; e += gridDim.x * 256) {
        int t = e / (BATCH * INDIM);
        int r = e - t * (BATCH * INDIM);
        int b = r >> 5, j = r & 31;
        float v;
        if (j < XDIM) v = x[(t * BATCH + b) * XDIM + j] * mask[(t * BATCH + b) * XDIM + j];
        else          v = a[(t * BATCH + b) * ADIM + (j - XDIM)];
        xa[e] = f2bf(v);
    }
    unsigned* h0 = (unsigned*)(ws + HB_OFF(0));
    unsigned* h1 = (unsigned*)(ws + HB_OFF(1));
    unsigned* h2 = (unsigned*)(ws + HB_OFF(2));
    const int hn = HB_BYTES / 4;
    for (int e = blockIdx.x * 256 + threadIdx.x; e < hn; e += gridDim.x * 256) {
        h0[e] = 0u; h1[e] = SENT; h2[e] = SENT;
    }
}

// ---------------------------------------------------------------------------
// persistent LSTM: 256 blocks = 8 teams x 32 unit-blocks, 512 thr (8 waves).
// Team = XCD-aligned (bt = bid & 7 under round-robin dispatch; perf-only).
// Weights in VGPRs; xa A-fragment per-lane from global (kk0 MFMA pre-poll);
// h staged via LDS; in-wave gate transpose; ONE barrier/step; data-sentinel
// 3-ring over LLC (sc1 relaxed atomics). K loop = dual accumulators.
__global__ __launch_bounds__(512, 1) void lstm_persist_kernel(
    const float* __restrict__ W_ih, const float* __restrict__ W_hh,
    const float* __restrict__ b_ih, const float* __restrict__ b_hh,
    uint8_t* __restrict__ ws)
{
    __shared__ __align__(16) uint8_t smem[LDS_TOTAL];
    const int tid = threadIdx.x;
    const int bid = blockIdx.x;
    const int bt = bid & 7;            // team = XCD id (round-robin heuristic)
    const int ut = bid >> 3;           // unit tile 0..31
    const int b0 = bt * BT;
    const int ug0 = ut * UT;

    const unsigned short* xab = (const unsigned short*)(ws + XA_OFF);
    unsigned long long* hb[3] = {
        (unsigned long long*)(ws + HB_OFF(0)),
        (unsigned long long*)(ws + HB_OFF(1)),
        (unsigned long long*)(ws + HB_OFF(2)) };
    float* hfinal = (float*)(ws + HF_OFF);

    const int w  = tid >> 6, l = tid & 63;
    const int mt = w >> 2;             // m-tile (16 batch rows)
    const int ct = w & 3;              // col-tile: units ct*4..+3, all 4 gates
    const int c  = l & 15;             // MFMA col: gate c>>2, unit-sub c&3
    const int kq = l >> 4;             // k-quad
    const int grow = (c >> 2) * HID + ug0 + ct * 4 + (c & 3);

    // ---- B fragments -> registers (constant all 200 steps) ----
    bf16x8 wb[KK_N];
    wb[0] = pack8(W_ih + (size_t)grow * INDIM + kq * 8);
#pragma unroll
    for (int kk = 1; kk < KK_N; ++kk)
        wb[kk] = pack8(W_hh + (size_t)grow * HID + (kk - 1) * 32 + kq * 8);
    const float bias = b_ih[grow] + b_hh[grow];

    const int du = l & 3, rs = l >> 2;           // pointwise (unit-sub, row)
    const int prow = tid >> 4, pcol = tid & 15;  // staging (row, slot)
    float c_reg = 0.0f;

    float* scr = (float*)(smem + SCR_OFF + w * 1024);

    // per-lane xa A-fragment for s=0 (t = TSTEPS-1): row mt*16+c, k = kq*8..+8
    const int arow = mt * 16 + c;
    bf16x8 af_cur = *(const bf16x8*)(xab +
        ((size_t)(TSTEPS - 1) * BATCH + b0 + arow) * 32 + kq * 8);

    for (int s = 0; s < TSTEPS; ++s) {
        uint8_t* inb = smem + (s & 1) * IN_BYTES;

        // ---- kk0 (xa) MFMA from registers, before the poll ----
        f32x4 acc = { bias, bias, bias, bias };
        acc = __builtin_amdgcn_mfma_f32_16x16x32_bf16(af_cur, wb[0], acc, 0, 0, 0);
        // prefetch next step's xa fragment (L2-resident)
        if (s < TSTEPS - 1)
            af_cur = *(const bf16x8*)(xab +
                ((size_t)(TSTEPS - 2 - s) * BATCH + b0 + arow) * 32 + kq * 8);

        // ---- poll + stage h(s): thread owns 8 u64 slots of row (b0+prow) ----
        {
            const unsigned long long* hr = hb[s % 3] + (((size_t)(b0 + prow)) << 7);
            unsigned long long vals[8];
            unsigned vm = 0;
#pragma unroll
            for (int j = 0; j < 8; ++j) vals[j] = llc_load64(hr + pcol + 16 * j);
            int rounds = 0;
            while (true) {
#pragma unroll
                for (int j = 0; j < 8; ++j) {
                    if (!(vm & (1u << j))) {
                        unsigned lo = (unsigned)vals[j];
                        unsigned hi = (unsigned)(vals[j] >> 32);
                        if (lo != SENT && hi != SENT) vm |= 1u << j;
                    }
                }
                if (vm == 0xFFu || rounds > (1 << 20)) break;
                __builtin_amdgcn_s_sleep(1);
                ++rounds;
#pragma unroll
                for (int j = 0; j < 8; ++j)
                    if (!(vm & (1u << j))) vals[j] = llc_load64(hr + pcol + 16 * j);
            }
#pragma unroll
            for (int j = 0; j < 8; ++j)
                *(unsigned long long*)(inb + prow * ROWB + (pcol + 16 * j) * 8) = vals[j];
        }

        // sentinel-reset own slice of ring buf (s+2)%3 (safe post-poll;
        // drains inside the barrier's vmcnt, off the producer->consumer edge)
        if (s >= 1 && tid < 128) {
            unsigned long long* rb = hb[(s + 2) % 3]
                + (((size_t)(b0 + (tid >> 2))) << 7) + ut * 4 + (tid & 3);
            llc_store64(rb, ~0ULL);
        }

        __syncthreads();

        // ---- MFMA kk1..16: dual accumulators (two 8-deep chains) ----
        const uint8_t* ab = inb + arow * ROWB + kq * 16;
        f32x4 acc1 = { 0.f, 0.f, 0.f, 0.f };
#pragma unroll
        for (int kk = 1; kk < KK_N; kk += 2) {
            bf16x8 afA = *(const bf16x8*)(ab + (kk - 1) * 64);
            acc  = __builtin_amdgcn_mfma_f32_16x16x32_bf16(afA, wb[kk], acc, 0, 0, 0);
            bf16x8 afB = *(const bf16x8*)(ab + kk * 64);
            acc1 = __builtin_amdgcn_mfma_f32_16x16x32_bf16(afB, wb[kk + 1], acc1, 0, 0, 0);
        }
        acc = acc + acc1;

        // ---- in-wave gate transpose via per-wave scratch (no barrier) ----
        *(f32x4*)(scr + l * 4) = acc;
        float gi = scr[(((rs >> 2) * 16 +  0 + du) << 2) + (rs & 3)];
        float gf = scr[(((rs >> 2) * 16 +  4 + du) << 2) + (rs & 3)];
        float gg = scr[(((rs >> 2) * 16 +  8 + du) << 2) + (rs & 3)];
        float go = scr[(((rs >> 2) * 16 + 12 + du) << 2) + (rs & 3)];

        float i_ = 1.0f / (1.0f + __expf(-gi));
        float f_ = 1.0f / (1.0f + __expf(-gf));
        float o_ = 1.0f / (1.0f + __expf(-go));
        float g_ = 1.0f - 2.0f / (__expf(2.0f * gg) + 1.0f);
        c_reg = f_ * c_reg + i_ * g_;
        float h_ = o_ * (1.0f - 2.0f / (__expf(2.0f * c_reg) + 1.0f));

        const int grow_b = b0 + mt * 16 + rs;          // global batch row
        if (s < TSTEPS - 1) {
            // pack this wave's 4 units -> u64, store by du==0 lanes
            unsigned v = (unsigned)f2bf(h_);
            unsigned t1 = (unsigned)__shfl_xor((int)v, 1);
            unsigned packed = v | (t1 << 16);
            unsigned hi = (unsigned)__shfl_xor((int)packed, 2);
            if (du == 0)
                llc_store64(hb[(s + 1) % 3] + (size_t)grow_b * 128 + ut * 4 + ct,
                            (unsigned long long)packed | ((unsigned long long)hi << 32));
        } else {
            hfinal[(size_t)grow_b * HID + ug0 + ct * 4 + du] = h_;
        }
    }
}

// ---------------------------------------------------------------------------
// heads: mu = exp(h@lin_w.T + lin_b)/10 ; log_var = h@lv_w.T + lv_b - 5
__global__ __launch_bounds__(128) void head_kernel(
    const float* __restrict__ h,
    const float* __restrict__ lin_w, const float* __restrict__ lin_b,
    const float* __restrict__ lv_w,  const float* __restrict__ lv_b,
    float* __restrict__ out)
{
    __shared__ float hl[HID];
    const int b = blockIdx.x, tid = threadIdx.x;
    for (int k = tid; k < HID; k += 128) hl[k] = h[b * HID + k];
    __syncthreads();

    const float* W = (tid < 64) ? lin_w : lv_w;
    const int j = tid & 63;
    const float4* W4 = (const float4*)(W + j * HID);
    float acc = 0.0f;
    for (int k4 = 0; k4 < HID / 4; ++k4) {
        float4 wv = W4[k4];
        float4 hv = *(const float4*)(hl + k4 * 4);
        acc += wv.x * hv.x + wv.y * hv.y + wv.z * hv.z + wv.w * hv.w;
    }

    if (tid < 64) {
        out[b * OUTD + j] = __expf(acc + lin_b[j]) * 0.1f;
    } else {
        out[BATCH * OUTD + b * OUTD + j] = acc + lv_b[j] - 5.0f;
    }
}

// ---------------------------------------------------------------------------
extern "C" void kernel_launch(void* const* d_in, const int* in_sizes, int n_in,
                              void* d_out, int out_size, void* d_ws, size_t ws_size,
                              hipStream_t stream)
{
    const float* x     = (const float*)d_in[0];
    const float* a     = (const float*)d_in[1];
    const float* mask  = (const float*)d_in[2];
    const float* W_ih  = (const float*)d_in[3];
    const float* W_hh  = (const float*)d_in[4];
    const float* b_ih  = (const float*)d_in[5];
    const float* b_hh  = (const float*)d_in[6];
    const float* lin_w = (const float*)d_in[7];
    const float* lin_b = (const float*)d_in[8];
    const float* lv_w  = (const float*)d_in[9];
    const float* lv_b  = (const float*)d_in[10];

    uint8_t* ws = (uint8_t*)d_ws;

    precompute_kernel<<<512, 256, 0, stream>>>(x, a, mask, ws);
    lstm_persist_kernel<<<NBT * NUT, 512, 0, stream>>>(W_ih, W_hh, b_ih, b_hh, ws);
    head_kernel<<<BATCH, 128, 0, stream>>>((const float*)(ws + HF_OFF),
                                           lin_w, lin_b, lv_w, lv_b, (float*)d_out);
}